// Round 1
// baseline (615.132 us; speedup 1.0000x reference)
//
#include <hip/hip_runtime.h>
#include <math.h>

#define F_   257
#define N_   1000
#define C_   6
#define S_   2
#define K_   4
#define T_   5
#define DLY  6          /* N_TAPS + N_DELAY */
#define EPSF 1e-3f
#define MODEL_EPSF 1e-5f
#define PB_EPSD 1e-6

__device__ __forceinline__ float2 cmul(float2 a, float2 b){
  return make_float2(a.x*b.x - a.y*b.y, a.x*b.y + a.y*b.x);
}
__device__ __forceinline__ float2 cadd(float2 a, float2 b){ return make_float2(a.x+b.x, a.y+b.y); }
__device__ __forceinline__ float2 csub(float2 a, float2 b){ return make_float2(a.x-b.x, a.y-b.y); }

struct dc { double x, y; };
__device__ __forceinline__ dc dmul(dc a, dc b){ return dc{a.x*b.x - a.y*b.y, a.x*b.y + a.y*b.x}; }
__device__ __forceinline__ dc dadd(dc a, dc b){ return dc{a.x+b.x, a.y+b.y}; }
__device__ __forceinline__ dc dsub(dc a, dc b){ return dc{a.x-b.x, a.y-b.y}; }
__device__ __forceinline__ dc ddiv(dc a, dc b){
  double d = b.x*b.x + b.y*b.y;
  return dc{(a.x*b.x + a.y*b.y)/d, (a.y*b.x - a.x*b.y)/d};
}
__device__ __forceinline__ dc d_of(float2 a){ return dc{(double)a.x, (double)a.y}; }

// ---------------------------------------------------------------------------
// K0: per-(b,f) covariances + state init.
// Cxx[p][c][d]    = sum_n X[c][n] conj(X[d][n]) / N
// Cbx[p][d][t][c] = sum_n X[d][n-(DLY-t)] conj(X[c][n]) / N   (zero-padded)
// ---------------------------------------------------------------------------
__global__ __launch_bounds__(256) void k_init(const float* __restrict__ Xre,
    const float* __restrict__ Xim, float2* __restrict__ Yg, float2* __restrict__ Wg,
    float2* __restrict__ Hg, float2* __restrict__ Cxxg, float2* __restrict__ Cbxg)
{
  __shared__ float2 Xl[C_*N_];
  int p = blockIdx.x; int b = p / F_; int f = p - b*F_;
  int tid = threadIdx.x;

  for (int i = tid; i < C_*N_; i += 256){
    int c = i / N_, n = i - c*N_;
    size_t gi = ((size_t)(b*C_+c)*F_ + f)*N_ + n;
    Xl[i] = make_float2(Xre[gi], Xim[gi]);
  }
  __syncthreads();

  for (int i = tid; i < S_*N_; i += 256){
    int s = i / N_, n = i - s*N_;
    Yg[((size_t)p*S_+s)*N_+n] = Xl[s*N_+n];
  }
  if (tid < S_*C_){
    int s = tid / C_, c = tid - s*C_;
    Wg[p*S_*C_ + tid] = make_float2((s==c) ? 1.f : 0.f, 0.f);
  }
  if (tid < S_*C_*T_)
    Hg[p*S_*C_*T_ + tid] = make_float2(0.f, 0.f);

  int wid = tid >> 6, lane = tid & 63;
  const float inv_n = 1.0f / (float)N_;
  for (int e = wid; e < 216; e += 4){
    int a_ch, b_ch, lag; float2* outp;
    if (e < 36){
      a_ch = e / 6; b_ch = e - a_ch*6; lag = 0;
      outp = &Cxxg[((size_t)p*C_ + a_ch)*C_ + b_ch];
    } else {
      int i2 = e - 36;
      int d = i2 / (T_*C_); int t = (i2 / C_) % T_; int c2 = i2 % C_;
      a_ch = d; b_ch = c2; lag = DLY - t;
      outp = &Cbxg[(((size_t)p*C_ + d)*T_ + t)*C_ + c2];
    }
    float accx = 0.f, accy = 0.f;
    for (int n = lane; n < N_; n += 64){
      if (n >= lag){
        float2 xa = Xl[a_ch*N_ + n - lag];
        float2 xb = Xl[b_ch*N_ + n];
        accx += xa.x*xb.x + xa.y*xb.y;   // xa * conj(xb)
        accy += xa.y*xb.x - xa.x*xb.y;
      }
    }
    #pragma unroll
    for (int off = 32; off; off >>= 1){
      accx += __shfl_xor(accx, off);
      accy += __shfl_xor(accy, off);
    }
    if (lane == 0) *outp = make_float2(accx*inv_n, accy*inv_n);
  }
}

// ---------------------------------------------------------------------------
// KW: den[b][s][n] = sum_f |Y[b,s,f,n]|^2 ; gsum[b][s] += partial sums
// grid = B*S_*8 blocks of 128 threads; each block owns 125 frames.
// ---------------------------------------------------------------------------
__global__ __launch_bounds__(128) void k_weights(const float2* __restrict__ Yg,
    float* __restrict__ deng, float* __restrict__ gsumg)
{
  __shared__ float redw[2];
  int blk = blockIdx.x;
  int ch = blk & 7; int s = (blk >> 3) & 1; int b = blk >> 4;
  int tid = threadIdx.x;
  int n = ch*125 + tid;
  float acc = 0.f;
  if (tid < 125){
    for (int f = 0; f < F_; ++f){
      float2 y = Yg[(((size_t)b*F_ + f)*S_ + s)*N_ + n];
      acc += y.x*y.x + y.y*y.y;
    }
    deng[(b*S_+s)*N_ + n] = acc;
  }
  float r = acc;
  #pragma unroll
  for (int off = 32; off; off >>= 1) r += __shfl_xor(r, off);
  if ((tid & 63) == 0) redw[tid >> 6] = r;
  __syncthreads();
  if (tid == 0) atomicAdd(&gsumg[b*S_+s], redw[0] + redw[1]);
}

// ---------------------------------------------------------------------------
// background update: A[s][j] = sum_i W[s][i] Cxx[i][j] + sum_{i,t} H[s][i][t] Cbx[i][t][j]
// solve A[:, :2] X = A[:, 2:], J[k][i] = conj(X[i][k])
// ---------------------------------------------------------------------------
__device__ __forceinline__ void bg_update(int tid, int p, const float2* Wl,
    const float2* Hl, float2* Al, float2* Jl,
    const float2* __restrict__ Cxxg, const float2* __restrict__ Cbxg)
{
  if (tid < S_*C_){
    int s = tid / C_, j = tid - s*C_;
    float2 a = make_float2(0.f, 0.f);
    const float2* cx = Cxxg + (size_t)p*C_*C_;
    #pragma unroll
    for (int i = 0; i < C_; ++i) a = cadd(a, cmul(Wl[s*C_+i], cx[i*C_+j]));
    const float2* cb = Cbxg + (size_t)p*C_*T_*C_;
    #pragma unroll
    for (int i = 0; i < C_; ++i)
      #pragma unroll
      for (int t = 0; t < T_; ++t)
        a = cadd(a, cmul(Hl[(s*C_+i)*T_+t], cb[(i*T_+t)*C_+j]));
    Al[s*C_+j] = a;
  }
  __syncthreads();
  if (tid == 0){
    dc M00 = d_of(Al[0]),  M01 = d_of(Al[1]);
    dc M10 = d_of(Al[C_]), M11 = d_of(Al[C_+1]);
    dc det = dsub(dmul(M00, M11), dmul(M01, M10));
    #pragma unroll
    for (int k = 0; k < K_; ++k){
      dc r0 = d_of(Al[2+k]), r1 = d_of(Al[C_+2+k]);
      dc x0 = ddiv(dsub(dmul(M11, r0), dmul(M01, r1)), det);
      dc x1 = ddiv(dsub(dmul(M00, r1), dmul(M10, r0)), det);
      Jl[k*S_+0] = make_float2((float)x0.x, (float)(-x0.y));
      Jl[k*S_+1] = make_float2((float)x1.x, (float)(-x1.y));
    }
  }
  __syncthreads();
}

// ---------------------------------------------------------------------------
// one ISS round: v[c] from block reduction over n, then Y[c] -= v[c]*s(n).
// caller applies W/H updates and issues the trailing __syncthreads().
// ---------------------------------------------------------------------------
template<typename FS>
__device__ __forceinline__ void iss_round(int tid, float2* Yl, const float* wl,
    float2* vl, float* red, FS sfun, bool isV1, int src)
{
  float r0=0,r1=0,r2=0,r3=0,r4=0,r5=0;
  for (int n = tid; n < N_; n += 256){
    float2 sv = sfun(n);
    float m = sv.x*sv.x + sv.y*sv.y;
    float w0 = wl[n], w1 = wl[N_+n];
    float2 y0 = Yl[n], y1 = Yl[N_+n];
    r0 += w0*(y0.x*sv.x + y0.y*sv.y);   // y * conj(s)
    r1 += w0*(y0.y*sv.x - y0.x*sv.y);
    r2 += w0*m;
    r3 += w1*(y1.x*sv.x + y1.y*sv.y);
    r4 += w1*(y1.y*sv.x - y1.x*sv.y);
    r5 += w1*m;
  }
  #pragma unroll
  for (int off = 32; off; off >>= 1){
    r0 += __shfl_xor(r0, off); r1 += __shfl_xor(r1, off);
    r2 += __shfl_xor(r2, off); r3 += __shfl_xor(r3, off);
    r4 += __shfl_xor(r4, off); r5 += __shfl_xor(r5, off);
  }
  if ((tid & 63) == 0){
    float* rw = red + (tid >> 6)*6;
    rw[0]=r0; rw[1]=r1; rw[2]=r2; rw[3]=r3; rw[4]=r4; rw[5]=r5;
  }
  __syncthreads();
  if (tid == 0){
    float t0 = red[0]+red[6]+red[12]+red[18];
    float t1 = red[1]+red[7]+red[13]+red[19];
    float t2 = red[2]+red[8]+red[14]+red[20];
    float t3 = red[3]+red[9]+red[15]+red[21];
    float t4 = red[4]+red[10]+red[16]+red[22];
    float t5 = red[5]+red[11]+red[17]+red[23];
    if (isV1){
      const float inv = 1.f/(float)N_;
      t0*=inv; t1*=inv; t2*=inv; t3*=inv; t4*=inv; t5*=inv;
    }
    float d0 = fmaxf(t2, EPSF), d1 = fmaxf(t5, EPSF);
    float2 v0 = make_float2(t0/d0, t1/d0);
    float2 v1 = make_float2(t3/d1, t4/d1);
    if (isV1){
      if (src == 0) v0 = make_float2(1.f - 1.f/sqrtf(d0), 0.f);
      else          v1 = make_float2(1.f - 1.f/sqrtf(d1), 0.f);
    }
    vl[0] = v0; vl[1] = v1;
  }
  __syncthreads();
  float2 v0 = vl[0], v1 = vl[1];
  for (int n = tid; n < N_; n += 256){
    float2 sv = sfun(n);              // old values: each thread owns its n
    Yl[n]    = csub(Yl[n],    cmul(v0, sv));
    Yl[N_+n] = csub(Yl[N_+n], cmul(v1, sv));
  }
}

// ---------------------------------------------------------------------------
// KM: one full _one_iter for one (b,f). FINAL adds demix+projection+output.
// ---------------------------------------------------------------------------
template<bool FINAL>
__global__ __launch_bounds__(256) void k_main(const float* __restrict__ Xre,
    const float* __restrict__ Xim, float2* __restrict__ Yg, float2* __restrict__ Wg,
    float2* __restrict__ Hg, const float2* __restrict__ Cxxg,
    const float2* __restrict__ Cbxg, const float* __restrict__ deng,
    const float* __restrict__ gsumg, float2* __restrict__ out2)
{
  extern __shared__ unsigned char smem_raw[];
  float2* Xl = (float2*)smem_raw;           // [C_][N_]
  float2* Yl = Xl + C_*N_;                  // [S_][N_]
  float*  wl = (float*)(Yl + S_*N_);        // [S_][N_]
  float2* Wl = (float2*)(wl + S_*N_);       // [S_][C_]
  float2* Hl = Wl + S_*C_;                  // [S_][C_][T_]
  float2* Jl = Hl + S_*C_*T_;               // [K_][S_]
  float2* Al = Jl + K_*S_;                  // [S_][C_]
  float2* vl = Al + S_*C_;                  // [S_]
  float*  red = (float*)(vl + S_);          // [4][6]

  int p = blockIdx.x; int b = p / F_; int f = p - b*F_;
  int tid = threadIdx.x;

  for (int i = tid; i < C_*N_; i += 256){
    int c = i / N_, n = i - c*N_;
    size_t gi = ((size_t)(b*C_+c)*F_ + f)*N_ + n;
    Xl[i] = make_float2(Xre[gi], Xim[gi]);
  }

  float gv0 = fmaxf(gsumg[b*S_+0] * (1.f/((float)F_*(float)N_)), EPSF);
  float gv1 = fmaxf(gsumg[b*S_+1] * (1.f/((float)F_*(float)N_)), EPSF);
  float ig0 = 1.f / fmaxf(sqrtf(gv0), EPSF);
  float ig1 = 1.f / fmaxf(sqrtf(gv1), EPSF);

  for (int n = tid; n < N_; n += 256){
    float2 y0 = Yg[((size_t)p*S_+0)*N_+n];
    float2 y1 = Yg[((size_t)p*S_+1)*N_+n];
    Yl[n]    = make_float2(y0.x*ig0, y0.y*ig0);
    Yl[N_+n] = make_float2(y1.x*ig1, y1.y*ig1);
    wl[n]    = gv0 / fmaxf(2.f*sqrtf(deng[(b*S_+0)*N_+n]), MODEL_EPSF);
    wl[N_+n] = gv1 / fmaxf(2.f*sqrtf(deng[(b*S_+1)*N_+n]), MODEL_EPSF);
  }
  if (tid < S_*C_){
    float ig = (tid / C_) ? ig1 : ig0;
    float2 w = Wg[(size_t)p*S_*C_ + tid];
    Wl[tid] = make_float2(w.x*ig, w.y*ig);
  }
  if (tid < S_*C_*T_){
    float ig = (tid / (C_*T_)) ? ig1 : ig0;
    float2 h = Hg[(size_t)p*S_*C_*T_ + tid];
    Hl[tid] = make_float2(h.x*ig, h.y*ig);
  }
  __syncthreads();

  bg_update(tid, p, Wl, Hl, Al, Jl, Cxxg, Cbxg);

  // ---- ISS: source rounds ----
  for (int src = 0; src < S_; ++src){
    iss_round(tid, Yl, wl, vl, red,
        [&](int n){ return Yl[src*N_+n]; }, true, src);
    if (tid < C_){
      float2 ws = Wl[src*C_+tid];
      Wl[tid]     = csub(Wl[tid],     cmul(vl[0], ws));
      Wl[C_+tid]  = csub(Wl[C_+tid],  cmul(vl[1], ws));
    } else if (tid >= 64 && tid < 64 + C_*T_){
      int i = tid - 64;
      float2 hs = Hl[src*C_*T_+i];
      Hl[i]         = csub(Hl[i],         cmul(vl[0], hs));
      Hl[C_*T_+i]   = csub(Hl[C_*T_+i],   cmul(vl[1], hs));
    }
    __syncthreads();
  }

  // ---- ISS: background rounds (Z recomputed on the fly) ----
  for (int bak = 0; bak < K_; ++bak){
    iss_round(tid, Yl, wl, vl, red,
        [&](int n){
          float2 z = cmul(Jl[bak*S_+0], Xl[n]);
          z = cadd(z, cmul(Jl[bak*S_+1], Xl[N_+n]));
          return csub(z, Xl[(S_+bak)*N_+n]);
        }, false, 0);
    if (tid < S_){
      float2 v = vl[tid];
      Wl[tid*C_+0]       = csub(Wl[tid*C_+0], cmul(v, Jl[bak*S_+0]));
      Wl[tid*C_+1]       = csub(Wl[tid*C_+1], cmul(v, Jl[bak*S_+1]));
      Wl[tid*C_+S_+bak]  = cadd(Wl[tid*C_+S_+bak], v);
    }
    __syncthreads();
  }

  // ---- ISS: tap rounds ----
  for (int sc = 0; sc < C_; ++sc){
    for (int tap = 0; tap < T_; ++tap){
      int lag = DLY - tap;
      iss_round(tid, Yl, wl, vl, red,
          [&](int n){ return (n >= lag) ? Xl[sc*N_ + n - lag]
                                        : make_float2(0.f, 0.f); },
          false, 0);
      if (tid < S_)
        Hl[(tid*C_+sc)*T_+tap] = cadd(Hl[(tid*C_+sc)*T_+tap], vl[tid]);
      __syncthreads();
    }
  }

  if (!FINAL){
    for (int n = tid; n < N_; n += 256){
      Yg[((size_t)p*S_+0)*N_+n] = Yl[n];
      Yg[((size_t)p*S_+1)*N_+n] = Yl[N_+n];
    }
    if (tid < S_*C_)    Wg[(size_t)p*S_*C_ + tid]    = Wl[tid];
    if (tid < S_*C_*T_) Hg[(size_t)p*S_*C_*T_ + tid] = Hl[tid];
  } else {
    // final background update with post-ISS W,H
    bg_update(tid, p, Wl, Hl, Al, Jl, Cxxg, Cbxg);

    // demix + dereverberation: Y = W X - H X_bar
    for (int n = tid; n < N_; n += 256){
      float2 a0 = make_float2(0.f,0.f), a1 = make_float2(0.f,0.f);
      #pragma unroll
      for (int d = 0; d < C_; ++d){
        float2 x = Xl[d*N_+n];
        a0 = cadd(a0, cmul(Wl[d],     x));
        a1 = cadd(a1, cmul(Wl[C_+d],  x));
      }
      #pragma unroll
      for (int t = 0; t < T_; ++t){
        int m = n - (DLY - t);
        if (m >= 0){
          #pragma unroll
          for (int d = 0; d < C_; ++d){
            float2 x = Xl[d*N_+m];
            a0 = csub(a0, cmul(Hl[(0*C_+d)*T_+t], x));
            a1 = csub(a1, cmul(Hl[(1*C_+d)*T_+t], x));
          }
        }
      }
      Yl[n] = a0; Yl[N_+n] = a1;
    }
    if (tid == 0){
      // projection back: B[s][k] = sum_c W2[s][c] J[c][k] + W1[s][k]
      dc Bm[2][2];
      #pragma unroll
      for (int s2 = 0; s2 < S_; ++s2)
        #pragma unroll
        for (int k = 0; k < S_; ++k){
          dc acc = d_of(Wl[s2*C_+k]);
          #pragma unroll
          for (int c = 0; c < K_; ++c)
            acc = dadd(acc, dmul(d_of(Wl[s2*C_+S_+c]), d_of(Jl[c*S_+k])));
          Bm[s2][k] = acc;
        }
      // G[i][j] = Bm[j][i] + eps*delta_ij ; solve G a = [1,0]^T
      dc G00 = dc{Bm[0][0].x + PB_EPSD, Bm[0][0].y};
      dc G01 = Bm[1][0];
      dc G10 = Bm[0][1];
      dc G11 = dc{Bm[1][1].x + PB_EPSD, Bm[1][1].y};
      dc det = dsub(dmul(G00, G11), dmul(G01, G10));
      dc a0 = ddiv(G11, det);
      dc a1 = ddiv(dc{-G10.x, -G10.y}, det);
      vl[0] = make_float2((float)a0.x, (float)a0.y);
      vl[1] = make_float2((float)a1.x, (float)a1.y);
    }
    __syncthreads();
    float2 s0 = vl[0], s1 = vl[1];
    for (int n = tid; n < N_; n += 256){
      out2[((size_t)(b*S_+0)*F_ + f)*N_ + n] = cmul(Yl[n],    s0);
      out2[((size_t)(b*S_+1)*F_ + f)*N_ + n] = cmul(Yl[N_+n], s1);
    }
  }
}

// ---------------------------------------------------------------------------
extern "C" void kernel_launch(void* const* d_in, const int* in_sizes, int n_in,
                              void* d_out, int out_size, void* d_ws, size_t ws_size,
                              hipStream_t stream)
{
  const float* Xre = (const float*)d_in[0];
  const float* Xim = (const float*)d_in[1];
  // n_src (d_in[2]) is fixed at 2 by the reference setup (S_).
  int B = in_sizes[0] / (C_*F_*N_);
  int P = B*F_;

  float2* Yg   = (float2*)d_ws;
  float2* Wg   = Yg   + (size_t)P*S_*N_;
  float2* Hg   = Wg   + (size_t)P*S_*C_;
  float2* Cxxg = Hg   + (size_t)P*S_*C_*T_;
  float2* Cbxg = Cxxg + (size_t)P*C_*C_;
  float*  deng = (float*)(Cbxg + (size_t)P*C_*T_*C_);
  float*  gsumg= deng + (size_t)B*S_*N_;     // 2 slots of B*S_ floats
  float2* out2 = (float2*)d_out;

  size_t smem = (size_t)(C_*N_ + S_*N_)*sizeof(float2)
              + (size_t)S_*N_*sizeof(float)
              + (size_t)(S_*C_ + S_*C_*T_ + K_*S_ + S_*C_ + S_)*sizeof(float2)
              + 24*sizeof(float);

  hipMemsetAsync(gsumg, 0, 2*(size_t)B*S_*sizeof(float), stream);
  k_init<<<P, 256, 0, stream>>>(Xre, Xim, Yg, Wg, Hg, Cxxg, Cbxg);

  // iteration 0
  k_weights<<<B*S_*8, 128, 0, stream>>>(Yg, deng, gsumg);
  k_main<false><<<P, 256, smem, stream>>>(Xre, Xim, Yg, Wg, Hg, Cxxg, Cbxg,
                                          deng, gsumg, nullptr);
  // iteration 1 + finalization
  k_weights<<<B*S_*8, 128, 0, stream>>>(Yg, deng, gsumg + B*S_);
  k_main<true><<<P, 256, smem, stream>>>(Xre, Xim, Yg, Wg, Hg, Cxxg, Cbxg,
                                         deng, gsumg + B*S_, out2);
}

// Round 2
// 498.377 us; speedup vs baseline: 1.2343x; 1.2343x over previous
//
#include <hip/hip_runtime.h>
#include <math.h>

#define F_   257
#define N_   1000
#define C_   6
#define S_   2
#define K_   4
#define T_   5
#define DLY  6          /* N_TAPS + N_DELAY */
#define EPSF 1e-3f
#define MODEL_EPSF 1e-5f
#define PB_EPSD 1e-6
#define NTHR 512

__device__ __forceinline__ float2 cmul(float2 a, float2 b){
  return make_float2(a.x*b.x - a.y*b.y, a.x*b.y + a.y*b.x);
}
__device__ __forceinline__ float2 cadd(float2 a, float2 b){ return make_float2(a.x+b.x, a.y+b.y); }
__device__ __forceinline__ float2 csub(float2 a, float2 b){ return make_float2(a.x-b.x, a.y-b.y); }

struct dc { double x, y; };
__device__ __forceinline__ dc dmul(dc a, dc b){ return dc{a.x*b.x - a.y*b.y, a.x*b.y + a.y*b.x}; }
__device__ __forceinline__ dc dadd(dc a, dc b){ return dc{a.x+b.x, a.y+b.y}; }
__device__ __forceinline__ dc dsub(dc a, dc b){ return dc{a.x-b.x, a.y-b.y}; }
__device__ __forceinline__ dc ddiv(dc a, dc b){
  double d = b.x*b.x + b.y*b.y;
  return dc{(a.x*b.x + a.y*b.y)/d, (a.y*b.x - a.x*b.y)/d};
}
__device__ __forceinline__ dc d_of(float2 a){ return dc{(double)a.x, (double)a.y}; }

struct V2 { float2 v0, v1; };

// ---------------------------------------------------------------------------
// K0: per-(b,f) covariances only.
// ---------------------------------------------------------------------------
__global__ __launch_bounds__(512) void k_init(const float* __restrict__ Xre,
    const float* __restrict__ Xim, float2* __restrict__ Cxxg, float2* __restrict__ Cbxg)
{
  __shared__ float2 Xl[C_*N_];
  int p = blockIdx.x; int b = p / F_; int f = p - b*F_;
  int tid = threadIdx.x;

  for (int i = tid; i < C_*N_; i += NTHR){
    int c = i / N_, n = i - c*N_;
    size_t gi = ((size_t)(b*C_+c)*F_ + f)*N_ + n;
    Xl[i] = make_float2(Xre[gi], Xim[gi]);
  }
  __syncthreads();

  int wid = tid >> 6, lane = tid & 63;
  const float inv_n = 1.0f / (float)N_;
  for (int e = wid; e < 216; e += 8){
    int a_ch, b_ch, lag; float2* outp;
    if (e < 36){
      a_ch = e / 6; b_ch = e - a_ch*6; lag = 0;
      outp = &Cxxg[((size_t)p*C_ + a_ch)*C_ + b_ch];
    } else {
      int i2 = e - 36;
      int d = i2 / (T_*C_); int t = (i2 / C_) % T_; int c2 = i2 % C_;
      a_ch = d; b_ch = c2; lag = DLY - t;
      outp = &Cbxg[(((size_t)p*C_ + d)*T_ + t)*C_ + c2];
    }
    float accx = 0.f, accy = 0.f;
    for (int n = lane; n < N_; n += 64){
      if (n >= lag){
        float2 xa = Xl[a_ch*N_ + n - lag];
        float2 xb = Xl[b_ch*N_ + n];
        accx += xa.x*xb.x + xa.y*xb.y;   // xa * conj(xb)
        accy += xa.y*xb.x - xa.x*xb.y;
      }
    }
    #pragma unroll
    for (int off = 32; off; off >>= 1){
      accx += __shfl_xor(accx, off);
      accy += __shfl_xor(accy, off);
    }
    if (lane == 0) *outp = make_float2(accx*inv_n, accy*inv_n);
  }
}

// ---------------------------------------------------------------------------
// weights precompute: den[b][s][n] = sum_f |Y|^2, gsum[b][s] = total
// grid = B*S*8(nchunk)*4(fchunk), block 128. den/gsum zeroed beforehand.
// ---------------------------------------------------------------------------
__global__ __launch_bounds__(128) void k_weights_x(const float* __restrict__ Xre,
    const float* __restrict__ Xim, float* __restrict__ deng, float* __restrict__ gsumg)
{
  __shared__ float redw[2];
  int blk = blockIdx.x;
  int fc = blk & 3; int ch = (blk >> 2) & 7; int s = (blk >> 5) & 1; int b = blk >> 6;
  int tid = threadIdx.x;
  int n = ch*125 + tid;
  int f0 = fc*65, f1 = (f0 + 65 < F_) ? f0 + 65 : F_;
  float acc = 0.f;
  if (tid < 125){
    for (int f = f0; f < f1; ++f){
      size_t gi = ((size_t)(b*C_+s)*F_ + f)*N_ + n;
      float xr = Xre[gi], xi = Xim[gi];
      acc += xr*xr + xi*xi;
    }
    atomicAdd(&deng[(b*S_+s)*N_ + n], acc);
  }
  float r = (tid < 125) ? acc : 0.f;
  #pragma unroll
  for (int off = 32; off; off >>= 1) r += __shfl_xor(r, off);
  if ((tid & 63) == 0) redw[tid >> 6] = r;
  __syncthreads();
  if (tid == 0) atomicAdd(&gsumg[b*S_+s], redw[0] + redw[1]);
}

__global__ __launch_bounds__(128) void k_weights_y(const float2* __restrict__ Yg,
    float* __restrict__ deng, float* __restrict__ gsumg)
{
  __shared__ float redw[2];
  int blk = blockIdx.x;
  int fc = blk & 3; int ch = (blk >> 2) & 7; int s = (blk >> 5) & 1; int b = blk >> 6;
  int tid = threadIdx.x;
  int n = ch*125 + tid;
  int f0 = fc*65, f1 = (f0 + 65 < F_) ? f0 + 65 : F_;
  float acc = 0.f;
  if (tid < 125){
    for (int f = f0; f < f1; ++f){
      float2 y = Yg[(((size_t)(b*F_+f))*S_ + s)*N_ + n];
      acc += y.x*y.x + y.y*y.y;
    }
    atomicAdd(&deng[(b*S_+s)*N_ + n], acc);
  }
  float r = (tid < 125) ? acc : 0.f;
  #pragma unroll
  for (int off = 32; off; off >>= 1) r += __shfl_xor(r, off);
  if ((tid & 63) == 0) redw[tid >> 6] = r;
  __syncthreads();
  if (tid == 0) atomicAdd(&gsumg[b*S_+s], redw[0] + redw[1]);
}

// ---------------------------------------------------------------------------
// background update (unchanged math; 2 internal barriers)
// ---------------------------------------------------------------------------
__device__ __forceinline__ void bg_update(int tid, int p, const float2* Wl,
    const float2* Hl, float2* Al, float2* Jl,
    const float2* __restrict__ Cxxg, const float2* __restrict__ Cbxg)
{
  if (tid < S_*C_){
    int s = tid / C_, j = tid - s*C_;
    float2 a = make_float2(0.f, 0.f);
    const float2* cx = Cxxg + (size_t)p*C_*C_;
    #pragma unroll
    for (int i = 0; i < C_; ++i) a = cadd(a, cmul(Wl[s*C_+i], cx[i*C_+j]));
    const float2* cb = Cbxg + (size_t)p*C_*T_*C_;
    #pragma unroll
    for (int i = 0; i < C_; ++i)
      #pragma unroll
      for (int t = 0; t < T_; ++t)
        a = cadd(a, cmul(Hl[(s*C_+i)*T_+t], cb[(i*T_+t)*C_+j]));
    Al[s*C_+j] = a;
  }
  __syncthreads();
  if (tid == 0){
    dc M00 = d_of(Al[0]),  M01 = d_of(Al[1]);
    dc M10 = d_of(Al[C_]), M11 = d_of(Al[C_+1]);
    dc det = dsub(dmul(M00, M11), dmul(M01, M10));
    #pragma unroll
    for (int k = 0; k < K_; ++k){
      dc r0 = d_of(Al[2+k]), r1 = d_of(Al[C_+2+k]);
      dc x0 = ddiv(dsub(dmul(M11, r0), dmul(M01, r1)), det);
      dc x1 = ddiv(dsub(dmul(M00, r1), dmul(M10, r0)), det);
      Jl[k*S_+0] = make_float2((float)x0.x, (float)(-x0.y));
      Jl[k*S_+1] = make_float2((float)x1.x, (float)(-x1.y));
    }
  }
  __syncthreads();
}

// ---------------------------------------------------------------------------
// one ISS round, register-resident Y/w, single barrier, redundant combine.
// ---------------------------------------------------------------------------
template<typename FS>
__device__ __forceinline__ V2 round2(int tid, bool hasB, int rb, float2* redv,
    float2& yA0, float2& yA1, float2& yB0, float2& yB1,
    float wA0, float wA1, float wB0, float wB1,
    FS sf, bool isV1, int src)
{
  float2 sA = sf(0), sB = sf(1);
  float m = sA.x*sA.x + sA.y*sA.y;
  float r0 = wA0*(yA0.x*sA.x + yA0.y*sA.y);   // y * conj(s)
  float r1 = wA0*(yA0.y*sA.x - yA0.x*sA.y);
  float r2 = wA0*m;
  float r3 = wA1*(yA1.x*sA.x + yA1.y*sA.y);
  float r4 = wA1*(yA1.y*sA.x - yA1.x*sA.y);
  float r5 = wA1*m;
  if (hasB){
    float mb = sB.x*sB.x + sB.y*sB.y;
    r0 += wB0*(yB0.x*sB.x + yB0.y*sB.y);
    r1 += wB0*(yB0.y*sB.x - yB0.x*sB.y);
    r2 += wB0*mb;
    r3 += wB1*(yB1.x*sB.x + yB1.y*sB.y);
    r4 += wB1*(yB1.y*sB.x - yB1.x*sB.y);
    r5 += wB1*mb;
  }
  #pragma unroll
  for (int off = 32; off; off >>= 1){
    r0 += __shfl_xor(r0, off); r1 += __shfl_xor(r1, off);
    r2 += __shfl_xor(r2, off); r3 += __shfl_xor(r3, off);
    r4 += __shfl_xor(r4, off); r5 += __shfl_xor(r5, off);
  }
  if ((tid & 63) == 0){
    float2* rw = redv + rb*24 + (tid >> 6)*3;
    rw[0] = make_float2(r0, r1);
    rw[1] = make_float2(r2, r3);
    rw[2] = make_float2(r4, r5);
  }
  __syncthreads();
  const float2* rp = redv + rb*24;
  float t0=0,t1=0,t2=0,t3=0,t4=0,t5=0;
  #pragma unroll
  for (int w = 0; w < 8; ++w){
    float2 a = rp[w*3], b2 = rp[w*3+1], c2 = rp[w*3+2];
    t0 += a.x; t1 += a.y; t2 += b2.x; t3 += b2.y; t4 += c2.x; t5 += c2.y;
  }
  if (isV1){
    const float inv = 1.f/(float)N_;
    t0*=inv; t1*=inv; t2*=inv; t3*=inv; t4*=inv; t5*=inv;
  }
  float d0 = fmaxf(t2, EPSF), d1 = fmaxf(t5, EPSF);
  float2 v0 = make_float2(t0/d0, t1/d0);
  float2 v1 = make_float2(t3/d1, t4/d1);
  if (isV1){
    if (src == 0) v0 = make_float2(1.f - 1.f/sqrtf(d0), 0.f);
    else          v1 = make_float2(1.f - 1.f/sqrtf(d1), 0.f);
  }
  yA0 = csub(yA0, cmul(v0, sA)); yA1 = csub(yA1, cmul(v1, sA));
  if (hasB){ yB0 = csub(yB0, cmul(v0, sB)); yB1 = csub(yB1, cmul(v1, sB)); }
  return V2{v0, v1};
}

// ---------------------------------------------------------------------------
// KM: one full _one_iter for one (b,f). FIRST: Y=X[:2], W=eye, H=0.
// FINAL: fuse final bg_update + demix-derev + projection-back + output.
// ---------------------------------------------------------------------------
template<bool FIRST, bool FINAL>
__global__ __launch_bounds__(512, 4) void k_main(const float* __restrict__ Xre,
    const float* __restrict__ Xim, float2* __restrict__ Yg, float2* __restrict__ Wg,
    float2* __restrict__ Hg, const float2* __restrict__ Cxxg,
    const float2* __restrict__ Cbxg, const float* __restrict__ deng,
    const float* __restrict__ gsumg, float2* __restrict__ out2, int P)
{
  __shared__ float2 Xl[C_*N_];
  __shared__ float2 Wl[S_*C_];
  __shared__ float2 Hl[S_*C_*T_];
  __shared__ float2 Jl[K_*S_];
  __shared__ float2 Al[S_*C_];
  __shared__ float2 redv[2*8*3];

  int tid = threadIdx.x;
  const int nA = tid;
  const int nB = tid + NTHR;
  const bool hasB = (nB < N_);
  const int nBs = hasB ? nB : 0;          // safe index for masked frame B

  for (int p = blockIdx.x; p < P; p += gridDim.x){
    __syncthreads();                       // protect Xl/Wl/Hl restage
    int b = p / F_, f = p - b*F_;

    for (int i = tid; i < C_*N_; i += NTHR){
      int c = i / N_, n = i - c*N_;
      size_t gi = ((size_t)(b*C_+c)*F_ + f)*N_ + n;
      Xl[i] = make_float2(Xre[gi], Xim[gi]);
    }

    float gv0 = fmaxf(gsumg[b*S_+0] * (1.f/((float)F_*(float)N_)), EPSF);
    float gv1 = fmaxf(gsumg[b*S_+1] * (1.f/((float)F_*(float)N_)), EPSF);
    float ig0 = 1.f / fmaxf(sqrtf(gv0), EPSF);
    float ig1 = 1.f / fmaxf(sqrtf(gv1), EPSF);

    float wA0 = gv0 / fmaxf(2.f*sqrtf(deng[(b*S_+0)*N_+nA]), MODEL_EPSF);
    float wA1 = gv1 / fmaxf(2.f*sqrtf(deng[(b*S_+1)*N_+nA]), MODEL_EPSF);
    float wB0 = 0.f, wB1 = 0.f;
    if (hasB){
      wB0 = gv0 / fmaxf(2.f*sqrtf(deng[(b*S_+0)*N_+nB]), MODEL_EPSF);
      wB1 = gv1 / fmaxf(2.f*sqrtf(deng[(b*S_+1)*N_+nB]), MODEL_EPSF);
    }

    if (FIRST){
      if (tid < S_*C_){
        int s = tid / C_, c = tid - s*C_;
        Wl[tid] = make_float2((s==c) ? (s ? ig1 : ig0) : 0.f, 0.f);
      }
      if (tid < S_*C_*T_) Hl[tid] = make_float2(0.f, 0.f);
    } else {
      if (tid < S_*C_){
        float ig = (tid / C_) ? ig1 : ig0;
        float2 w = Wg[(size_t)p*S_*C_ + tid];
        Wl[tid] = make_float2(w.x*ig, w.y*ig);
      }
      if (tid < S_*C_*T_){
        float ig = (tid / (C_*T_)) ? ig1 : ig0;
        float2 h = Hg[(size_t)p*S_*C_*T_ + tid];
        Hl[tid] = make_float2(h.x*ig, h.y*ig);
      }
    }
    __syncthreads();

    float2 xA0 = Xl[nA], xA1 = Xl[N_+nA];
    float2 xB0 = make_float2(0.f,0.f), xB1 = make_float2(0.f,0.f);
    if (hasB){ xB0 = Xl[nB]; xB1 = Xl[N_+nB]; }

    float2 yA0, yA1, yB0 = make_float2(0.f,0.f), yB1 = make_float2(0.f,0.f);
    if (FIRST){
      yA0 = make_float2(xA0.x*ig0, xA0.y*ig0);
      yA1 = make_float2(xA1.x*ig1, xA1.y*ig1);
      if (hasB){
        yB0 = make_float2(xB0.x*ig0, xB0.y*ig0);
        yB1 = make_float2(xB1.x*ig1, xB1.y*ig1);
      }
    } else {
      float2 t0 = Yg[((size_t)p*S_+0)*N_+nA];
      float2 t1 = Yg[((size_t)p*S_+1)*N_+nA];
      yA0 = make_float2(t0.x*ig0, t0.y*ig0);
      yA1 = make_float2(t1.x*ig1, t1.y*ig1);
      if (hasB){
        float2 u0 = Yg[((size_t)p*S_+0)*N_+nB];
        float2 u1 = Yg[((size_t)p*S_+1)*N_+nB];
        yB0 = make_float2(u0.x*ig0, u0.y*ig0);
        yB1 = make_float2(u1.x*ig1, u1.y*ig1);
      }
    }

    bg_update(tid, p, Wl, Hl, Al, Jl, Cxxg, Cbxg);

    int rr = 0;

    // ---- source rounds ----
    for (int src2 = 0; src2 < S_; ++src2){
      V2 v = round2(tid, hasB, (rr++)&1, redv, yA0,yA1,yB0,yB1, wA0,wA1,wB0,wB1,
          [&](int k)->float2 {
            return (src2 == 0) ? (k ? yB0 : yA0) : (k ? yB1 : yA1);
          }, true, src2);
      if (tid < C_){
        float2 ws = Wl[src2*C_+tid];
        Wl[tid]      = csub(Wl[tid],      cmul(v.v0, ws));
        Wl[C_+tid]   = csub(Wl[C_+tid],   cmul(v.v1, ws));
      } else if (tid >= 64 && tid < 64 + C_*T_){
        int i = tid - 64;
        float2 hs = Hl[src2*C_*T_+i];
        Hl[i]        = csub(Hl[i],        cmul(v.v0, hs));
        Hl[C_*T_+i]  = csub(Hl[C_*T_+i],  cmul(v.v1, hs));
      }
    }

    // ---- background rounds (Z on the fly) ----
    for (int bak = 0; bak < K_; ++bak){
      float2 J0 = Jl[bak*S_+0], J1 = Jl[bak*S_+1];
      V2 v = round2(tid, hasB, (rr++)&1, redv, yA0,yA1,yB0,yB1, wA0,wA1,wB0,wB1,
          [&](int k)->float2 {
            float2 x0 = k ? xB0 : xA0;
            float2 x1 = k ? xB1 : xA1;
            int n = k ? nBs : nA;
            float2 z = cadd(cmul(J0, x0), cmul(J1, x1));
            return csub(z, Xl[(S_+bak)*N_ + n]);
          }, false, 0);
      if (tid < S_){
        float2 vv = tid ? v.v1 : v.v0;
        Wl[tid*C_+0]      = csub(Wl[tid*C_+0], cmul(vv, J0));
        Wl[tid*C_+1]      = csub(Wl[tid*C_+1], cmul(vv, J1));
        Wl[tid*C_+S_+bak] = cadd(Wl[tid*C_+S_+bak], vv);
      }
    }

    // ---- tap rounds ----
    for (int sc = 0; sc < C_; ++sc){
      for (int tap = 0; tap < T_; ++tap){
        int lag = DLY - tap;
        V2 v = round2(tid, hasB, (rr++)&1, redv, yA0,yA1,yB0,yB1, wA0,wA1,wB0,wB1,
            [&](int k)->float2 {
              int n = (k ? nBs : nA) - lag;
              return (n >= 0) ? Xl[sc*N_ + n] : make_float2(0.f, 0.f);
            }, false, 0);
        if (tid < S_){
          int idx = (tid*C_+sc)*T_+tap;
          Hl[idx] = cadd(Hl[idx], tid ? v.v1 : v.v0);
        }
      }
    }

    __syncthreads();   // all W/H/Y updates visible

    if (!FINAL){
      Yg[((size_t)p*S_+0)*N_+nA] = yA0;
      Yg[((size_t)p*S_+1)*N_+nA] = yA1;
      if (hasB){
        Yg[((size_t)p*S_+0)*N_+nB] = yB0;
        Yg[((size_t)p*S_+1)*N_+nB] = yB1;
      }
      if (tid < S_*C_)    Wg[(size_t)p*S_*C_ + tid]    = Wl[tid];
      if (tid < S_*C_*T_) Hg[(size_t)p*S_*C_*T_ + tid] = Hl[tid];
    } else {
      bg_update(tid, p, Wl, Hl, Al, Jl, Cxxg, Cbxg);   // final J

      // demix + dereverberation from registers/LDS
      float2 oA0 = make_float2(0.f,0.f), oA1 = oA0, oB0 = oA0, oB1 = oA0;
      #pragma unroll
      for (int d = 0; d < C_; ++d){
        float2 x = Xl[d*N_+nA];
        oA0 = cadd(oA0, cmul(Wl[d],    x));
        oA1 = cadd(oA1, cmul(Wl[C_+d], x));
      }
      #pragma unroll
      for (int t = 0; t < T_; ++t){
        int m = nA - (DLY - t);
        if (m >= 0){
          #pragma unroll
          for (int d = 0; d < C_; ++d){
            float2 x = Xl[d*N_+m];
            oA0 = csub(oA0, cmul(Hl[d*T_+t],        x));
            oA1 = csub(oA1, cmul(Hl[(C_+d)*T_+t],   x));
          }
        }
      }
      if (hasB){
        #pragma unroll
        for (int d = 0; d < C_; ++d){
          float2 x = Xl[d*N_+nB];
          oB0 = cadd(oB0, cmul(Wl[d],    x));
          oB1 = cadd(oB1, cmul(Wl[C_+d], x));
        }
        #pragma unroll
        for (int t = 0; t < T_; ++t){
          int m = nB - (DLY - t);          // always >= 0
          #pragma unroll
          for (int d = 0; d < C_; ++d){
            float2 x = Xl[d*N_+m];
            oB0 = csub(oB0, cmul(Hl[d*T_+t],      x));
            oB1 = csub(oB1, cmul(Hl[(C_+d)*T_+t], x));
          }
        }
      }

      if (tid == 0){
        dc Bm[2][2];
        #pragma unroll
        for (int s2 = 0; s2 < S_; ++s2)
          #pragma unroll
          for (int k = 0; k < S_; ++k){
            dc acc = d_of(Wl[s2*C_+k]);
            #pragma unroll
            for (int c = 0; c < K_; ++c)
              acc = dadd(acc, dmul(d_of(Wl[s2*C_+S_+c]), d_of(Jl[c*S_+k])));
            Bm[s2][k] = acc;
          }
        dc G00 = dc{Bm[0][0].x + PB_EPSD, Bm[0][0].y};
        dc G01 = Bm[1][0];
        dc G10 = Bm[0][1];
        dc G11 = dc{Bm[1][1].x + PB_EPSD, Bm[1][1].y};
        dc det = dsub(dmul(G00, G11), dmul(G01, G10));
        dc a0 = ddiv(G11, det);
        dc a1 = ddiv(dc{-G10.x, -G10.y}, det);
        Al[0] = make_float2((float)a0.x, (float)a0.y);
        Al[1] = make_float2((float)a1.x, (float)a1.y);
      }
      __syncthreads();
      float2 s0 = Al[0], s1 = Al[1];
      out2[((size_t)(b*S_+0)*F_ + f)*N_ + nA] = cmul(oA0, s0);
      out2[((size_t)(b*S_+1)*F_ + f)*N_ + nA] = cmul(oA1, s1);
      if (hasB){
        out2[((size_t)(b*S_+0)*F_ + f)*N_ + nB] = cmul(oB0, s0);
        out2[((size_t)(b*S_+1)*F_ + f)*N_ + nB] = cmul(oB1, s1);
      }
    }
  }
}

// ---------------------------------------------------------------------------
extern "C" void kernel_launch(void* const* d_in, const int* in_sizes, int n_in,
                              void* d_out, int out_size, void* d_ws, size_t ws_size,
                              hipStream_t stream)
{
  const float* Xre = (const float*)d_in[0];
  const float* Xim = (const float*)d_in[1];
  int B = in_sizes[0] / (C_*F_*N_);
  int P = B*F_;

  float2* Yg   = (float2*)d_ws;
  float2* Wg   = Yg   + (size_t)P*S_*N_;
  float2* Hg   = Wg   + (size_t)P*S_*C_;
  float2* Cxxg = Hg   + (size_t)P*S_*C_*T_;
  float2* Cbxg = Cxxg + (size_t)P*C_*C_;
  float*  deng = (float*)(Cbxg + (size_t)P*C_*T_*C_);
  float*  gsumg= deng + (size_t)B*S_*N_;
  float2* out2 = (float2*)d_out;

  size_t denBytes = ((size_t)B*S_*N_ + (size_t)B*S_) * sizeof(float);
  int G = (P < 512) ? P : 512;
  int WG = B*S_*8*4;

  // iteration 0
  hipMemsetAsync(deng, 0, denBytes, stream);
  k_weights_x<<<WG, 128, 0, stream>>>(Xre, Xim, deng, gsumg);
  k_init<<<P, 512, 0, stream>>>(Xre, Xim, Cxxg, Cbxg);
  k_main<true,false><<<G, 512, 0, stream>>>(Xre, Xim, Yg, Wg, Hg, Cxxg, Cbxg,
                                            deng, gsumg, nullptr, P);
  // iteration 1 + finalization
  hipMemsetAsync(deng, 0, denBytes, stream);
  k_weights_y<<<WG, 128, 0, stream>>>(Yg, deng, gsumg);
  k_main<false,true><<<G, 512, 0, stream>>>(Xre, Xim, Yg, Wg, Hg, Cxxg, Cbxg,
                                            deng, gsumg, out2, P);
}

// Round 3
// 440.093 us; speedup vs baseline: 1.3977x; 1.1324x over previous
//
#include <hip/hip_runtime.h>
#include <math.h>

#define F_   257
#define N_   1000
#define C_   6
#define S_   2
#define K_   4
#define T_   5
#define DLY  6          /* N_TAPS + N_DELAY */
#define EPSF 1e-3f
#define MODEL_EPSF 1e-5f
#define PB_EPSD 1e-6
#define NTHR 512

__device__ __forceinline__ float2 cmul(float2 a, float2 b){
  return make_float2(a.x*b.x - a.y*b.y, a.x*b.y + a.y*b.x);
}
__device__ __forceinline__ float2 cadd(float2 a, float2 b){ return make_float2(a.x+b.x, a.y+b.y); }
__device__ __forceinline__ float2 csub(float2 a, float2 b){ return make_float2(a.x-b.x, a.y-b.y); }

struct dc { double x, y; };
__device__ __forceinline__ dc dmul(dc a, dc b){ return dc{a.x*b.x - a.y*b.y, a.x*b.y + a.y*b.x}; }
__device__ __forceinline__ dc dadd(dc a, dc b){ return dc{a.x+b.x, a.y+b.y}; }
__device__ __forceinline__ dc dsub(dc a, dc b){ return dc{a.x-b.x, a.y-b.y}; }
__device__ __forceinline__ dc ddiv(dc a, dc b){
  double d = b.x*b.x + b.y*b.y;
  return dc{(a.x*b.x + a.y*b.y)/d, (a.y*b.x - a.x*b.y)/d};
}
__device__ __forceinline__ dc d_of(float2 a){ return dc{(double)a.x, (double)a.y}; }

struct V2 { float2 v0, v1; };

// ---------------------------------------------------------------------------
// weights precompute: den[b][s][n] += sum_f |src|^2, gsum[b][s] += total
// grid = B*2*8*16, block 128 (125 active). den/gsum zeroed beforehand.
// ---------------------------------------------------------------------------
__global__ __launch_bounds__(128) void k_weights_x(const float* __restrict__ Xre,
    const float* __restrict__ Xim, float* __restrict__ deng, float* __restrict__ gsumg)
{
  __shared__ float redw[2];
  int blk = blockIdx.x;
  int fc = blk & 15; int ch = (blk >> 4) & 7; int s = (blk >> 7) & 1; int b = blk >> 8;
  int tid = threadIdx.x;
  int n = ch*125 + tid;
  int f0 = fc*17, f1 = (f0 + 17 < F_) ? f0 + 17 : F_;
  float acc = 0.f;
  if (tid < 125){
    for (int f = f0; f < f1; ++f){
      size_t gi = ((size_t)(b*C_+s)*F_ + f)*N_ + n;
      float xr = Xre[gi], xi = Xim[gi];
      acc += xr*xr + xi*xi;
    }
    atomicAdd(&deng[(b*S_+s)*N_ + n], acc);
  }
  float r = (tid < 125) ? acc : 0.f;
  #pragma unroll
  for (int off = 32; off; off >>= 1) r += __shfl_xor(r, off);
  if ((tid & 63) == 0) redw[tid >> 6] = r;
  __syncthreads();
  if (tid == 0) atomicAdd(&gsumg[b*S_+s], redw[0] + redw[1]);
}

__global__ __launch_bounds__(128) void k_weights_y(const float2* __restrict__ Yg,
    float* __restrict__ deng, float* __restrict__ gsumg)
{
  __shared__ float redw[2];
  int blk = blockIdx.x;
  int fc = blk & 15; int ch = (blk >> 4) & 7; int s = (blk >> 7) & 1; int b = blk >> 8;
  int tid = threadIdx.x;
  int n = ch*125 + tid;
  int f0 = fc*17, f1 = (f0 + 17 < F_) ? f0 + 17 : F_;
  float acc = 0.f;
  if (tid < 125){
    for (int f = f0; f < f1; ++f){
      float2 y = Yg[(((size_t)(b*F_+f))*S_ + s)*N_ + n];
      acc += y.x*y.x + y.y*y.y;
    }
    atomicAdd(&deng[(b*S_+s)*N_ + n], acc);
  }
  float r = (tid < 125) ? acc : 0.f;
  #pragma unroll
  for (int off = 32; off; off >>= 1) r += __shfl_xor(r, off);
  if ((tid & 63) == 0) redw[tid >> 6] = r;
  __syncthreads();
  if (tid == 0) atomicAdd(&gsumg[b*S_+s], redw[0] + redw[1]);
}

// ---------------------------------------------------------------------------
// background update; cx/cb are pre-offset pointers (LDS or global)
// ---------------------------------------------------------------------------
__device__ __forceinline__ void bg_update(int tid, const float2* Wl,
    const float2* Hl, float2* Al, float2* Jl,
    const float2* cx, const float2* cb)
{
  if (tid < S_*C_){
    int s = tid / C_, j = tid - s*C_;
    float2 a = make_float2(0.f, 0.f);
    #pragma unroll
    for (int i = 0; i < C_; ++i) a = cadd(a, cmul(Wl[s*C_+i], cx[i*C_+j]));
    #pragma unroll
    for (int i = 0; i < C_; ++i)
      #pragma unroll
      for (int t = 0; t < T_; ++t)
        a = cadd(a, cmul(Hl[(s*C_+i)*T_+t], cb[(i*T_+t)*C_+j]));
    Al[s*C_+j] = a;
  }
  __syncthreads();
  if (tid == 0){
    dc M00 = d_of(Al[0]),  M01 = d_of(Al[1]);
    dc M10 = d_of(Al[C_]), M11 = d_of(Al[C_+1]);
    dc det = dsub(dmul(M00, M11), dmul(M01, M10));
    #pragma unroll
    for (int k = 0; k < K_; ++k){
      dc r0 = d_of(Al[2+k]), r1 = d_of(Al[C_+2+k]);
      dc x0 = ddiv(dsub(dmul(M11, r0), dmul(M01, r1)), det);
      dc x1 = ddiv(dsub(dmul(M00, r1), dmul(M10, r0)), det);
      Jl[k*S_+0] = make_float2((float)x0.x, (float)(-x0.y));
      Jl[k*S_+1] = make_float2((float)x1.x, (float)(-x1.y));
    }
  }
  __syncthreads();
}

// ---------------------------------------------------------------------------
// one ISS round: register Y/w, single barrier, lane-split cross-wave combine.
// redl layout: [2 bufs][8 waves][8 slots] floats; slots 6,7 pre-zeroed.
// ---------------------------------------------------------------------------
template<typename FS>
__device__ __forceinline__ V2 round2(int tid, bool hasB, int rb, float* redl,
    float2& yA0, float2& yA1, float2& yB0, float2& yB1,
    float wA0, float wA1, float wB0, float wB1,
    FS sf, bool isV1, int src)
{
  float2 sA = sf(0), sB = sf(1);
  float m = sA.x*sA.x + sA.y*sA.y;
  float r0 = wA0*(yA0.x*sA.x + yA0.y*sA.y);   // y * conj(s)
  float r1 = wA0*(yA0.y*sA.x - yA0.x*sA.y);
  float r2 = wA0*m;
  float r3 = wA1*(yA1.x*sA.x + yA1.y*sA.y);
  float r4 = wA1*(yA1.y*sA.x - yA1.x*sA.y);
  float r5 = wA1*m;
  if (hasB){
    float mb = sB.x*sB.x + sB.y*sB.y;
    r0 += wB0*(yB0.x*sB.x + yB0.y*sB.y);
    r1 += wB0*(yB0.y*sB.x - yB0.x*sB.y);
    r2 += wB0*mb;
    r3 += wB1*(yB1.x*sB.x + yB1.y*sB.y);
    r4 += wB1*(yB1.y*sB.x - yB1.x*sB.y);
    r5 += wB1*mb;
  }
  #pragma unroll
  for (int off = 32; off; off >>= 1){
    r0 += __shfl_xor(r0, off); r1 += __shfl_xor(r1, off);
    r2 += __shfl_xor(r2, off); r3 += __shfl_xor(r3, off);
    r4 += __shfl_xor(r4, off); r5 += __shfl_xor(r5, off);
  }
  int lane = tid & 63, wid = tid >> 6;
  if (lane == 0){
    float2* rw = (float2*)(redl + rb*64 + wid*8);
    rw[0] = make_float2(r0, r1);
    rw[1] = make_float2(r2, r3);
    rw[2] = make_float2(r4, r5);
  }
  __syncthreads();
  float pv = ((lane & 7) < 6) ? redl[rb*64 + (lane >> 3)*8 + (lane & 7)] : 0.f;
  pv += __shfl_xor(pv, 8);
  pv += __shfl_xor(pv, 16);
  pv += __shfl_xor(pv, 32);
  float t0 = __shfl(pv, 0), t1 = __shfl(pv, 1), t2 = __shfl(pv, 2);
  float t3 = __shfl(pv, 3), t4 = __shfl(pv, 4), t5 = __shfl(pv, 5);
  if (isV1){
    const float inv = 1.f/(float)N_;
    t0*=inv; t1*=inv; t2*=inv; t3*=inv; t4*=inv; t5*=inv;
  }
  float d0 = fmaxf(t2, EPSF), d1 = fmaxf(t5, EPSF);
  float2 v0 = make_float2(t0/d0, t1/d0);
  float2 v1 = make_float2(t3/d1, t4/d1);
  if (isV1){
    if (src == 0) v0 = make_float2(1.f - 1.f/sqrtf(d0), 0.f);
    else          v1 = make_float2(1.f - 1.f/sqrtf(d1), 0.f);
  }
  yA0 = csub(yA0, cmul(v0, sA)); yA1 = csub(yA1, cmul(v1, sA));
  if (hasB){ yB0 = csub(yB0, cmul(v0, sB)); yB1 = csub(yB1, cmul(v1, sB)); }
  return V2{v0, v1};
}

// ---------------------------------------------------------------------------
// KM: one full _one_iter for one (b,f). FIRST: Y=X[:2], W=eye, H=0, computes
// covariances into LDS + global. FINAL: final bg + demix + PB + output.
// ---------------------------------------------------------------------------
template<bool FIRST, bool FINAL>
__global__ __launch_bounds__(512, 6) void k_main(const float* __restrict__ Xre,
    const float* __restrict__ Xim, float2* __restrict__ Yg, float2* __restrict__ Wg,
    float2* __restrict__ Hg, float2* __restrict__ Cxxg,
    float2* __restrict__ Cbxg, const float* __restrict__ deng,
    const float* __restrict__ gsumg, float2* __restrict__ out2)
{
  __shared__ float2 Xl[C_*N_];
  __shared__ float2 Wl[S_*C_];
  __shared__ float2 Hl[S_*C_*T_];
  __shared__ float2 Jl[K_*S_];
  __shared__ float2 Al[S_*C_];
  __shared__ float  redl[2*64];
  __shared__ float2 Cxl[C_*C_];
  __shared__ float2 Cbl[C_*T_*C_];

  int p = blockIdx.x; int b = p / F_; int f = p - b*F_;
  int tid = threadIdx.x;
  const int nA = tid;
  const int nB = tid + NTHR;
  const bool hasB = (nB < N_);
  const int nBs = hasB ? nB : 0;

  for (int i = tid; i < C_*N_; i += NTHR){
    int c = i / N_, n = i - c*N_;
    size_t gi = ((size_t)(b*C_+c)*F_ + f)*N_ + n;
    Xl[i] = make_float2(Xre[gi], Xim[gi]);
  }
  if (tid < 128) redl[tid] = 0.f;

  float gv0 = fmaxf(gsumg[b*S_+0] * (1.f/((float)F_*(float)N_)), EPSF);
  float gv1 = fmaxf(gsumg[b*S_+1] * (1.f/((float)F_*(float)N_)), EPSF);
  float ig0 = 1.f / fmaxf(sqrtf(gv0), EPSF);
  float ig1 = 1.f / fmaxf(sqrtf(gv1), EPSF);

  float wA0 = gv0 / fmaxf(2.f*sqrtf(deng[(b*S_+0)*N_+nA]), MODEL_EPSF);
  float wA1 = gv1 / fmaxf(2.f*sqrtf(deng[(b*S_+1)*N_+nA]), MODEL_EPSF);
  float wB0 = 0.f, wB1 = 0.f;
  if (hasB){
    wB0 = gv0 / fmaxf(2.f*sqrtf(deng[(b*S_+0)*N_+nB]), MODEL_EPSF);
    wB1 = gv1 / fmaxf(2.f*sqrtf(deng[(b*S_+1)*N_+nB]), MODEL_EPSF);
  }

  if (FIRST){
    if (tid < S_*C_){
      int s = tid / C_, c = tid - s*C_;
      Wl[tid] = make_float2((s==c) ? (s ? ig1 : ig0) : 0.f, 0.f);
    }
    if (tid < S_*C_*T_) Hl[tid] = make_float2(0.f, 0.f);
  } else {
    if (tid < S_*C_){
      float ig = (tid / C_) ? ig1 : ig0;
      float2 w = Wg[(size_t)p*S_*C_ + tid];
      Wl[tid] = make_float2(w.x*ig, w.y*ig);
    }
    if (tid < S_*C_*T_){
      float ig = (tid / (C_*T_)) ? ig1 : ig0;
      float2 h = Hg[(size_t)p*S_*C_*T_ + tid];
      Hl[tid] = make_float2(h.x*ig, h.y*ig);
    }
  }
  __syncthreads();

  if (FIRST){
    // covariances from staged Xl -> LDS (for our bg_update) + global (for pass 2)
    int wid = tid >> 6, lane = tid & 63;
    const float inv_n = 1.0f / (float)N_;
    for (int e = wid; e < 216; e += 8){
      int a_ch, b_ch, lag;
      if (e < 36){ a_ch = e / 6; b_ch = e - a_ch*6; lag = 0; }
      else {
        int i2 = e - 36;
        a_ch = i2 / (T_*C_); int t = (i2 / C_) % T_; b_ch = i2 % C_;
        lag = DLY - t;
      }
      float accx = 0.f, accy = 0.f;
      for (int n = lane; n < N_; n += 64){
        if (n >= lag){
          float2 xa = Xl[a_ch*N_ + n - lag];
          float2 xb = Xl[b_ch*N_ + n];
          accx += xa.x*xb.x + xa.y*xb.y;   // xa * conj(xb)
          accy += xa.y*xb.x - xa.x*xb.y;
        }
      }
      #pragma unroll
      for (int off = 32; off; off >>= 1){
        accx += __shfl_xor(accx, off);
        accy += __shfl_xor(accy, off);
      }
      if (lane == 0){
        float2 r = make_float2(accx*inv_n, accy*inv_n);
        if (e < 36){ Cxl[e] = r; Cxxg[(size_t)p*(C_*C_) + e] = r; }
        else { Cbl[e-36] = r; Cbxg[(size_t)p*(C_*T_*C_) + (e-36)] = r; }
      }
    }
    __syncthreads();
  }

  const float2* cx = FIRST ? (const float2*)Cxl : (const float2*)(Cxxg + (size_t)p*C_*C_);
  const float2* cb = FIRST ? (const float2*)Cbl : (const float2*)(Cbxg + (size_t)p*C_*T_*C_);

  float2 xA0 = Xl[nA], xA1 = Xl[N_+nA];
  float2 xB0 = make_float2(0.f,0.f), xB1 = make_float2(0.f,0.f);
  if (hasB){ xB0 = Xl[nB]; xB1 = Xl[N_+nB]; }

  float2 yA0, yA1, yB0 = make_float2(0.f,0.f), yB1 = make_float2(0.f,0.f);
  if (FIRST){
    yA0 = make_float2(xA0.x*ig0, xA0.y*ig0);
    yA1 = make_float2(xA1.x*ig1, xA1.y*ig1);
    if (hasB){
      yB0 = make_float2(xB0.x*ig0, xB0.y*ig0);
      yB1 = make_float2(xB1.x*ig1, xB1.y*ig1);
    }
  } else {
    float2 t0 = Yg[((size_t)p*S_+0)*N_+nA];
    float2 t1 = Yg[((size_t)p*S_+1)*N_+nA];
    yA0 = make_float2(t0.x*ig0, t0.y*ig0);
    yA1 = make_float2(t1.x*ig1, t1.y*ig1);
    if (hasB){
      float2 u0 = Yg[((size_t)p*S_+0)*N_+nB];
      float2 u1 = Yg[((size_t)p*S_+1)*N_+nB];
      yB0 = make_float2(u0.x*ig0, u0.y*ig0);
      yB1 = make_float2(u1.x*ig1, u1.y*ig1);
    }
  }

  bg_update(tid, Wl, Hl, Al, Jl, cx, cb);

  int rr = 0;

  // ---- source rounds ----
  for (int src2 = 0; src2 < S_; ++src2){
    V2 v = round2(tid, hasB, (rr++)&1, redl, yA0,yA1,yB0,yB1, wA0,wA1,wB0,wB1,
        [&](int k)->float2 {
          return (src2 == 0) ? (k ? yB0 : yA0) : (k ? yB1 : yA1);
        }, true, src2);
    if (tid < C_){
      float2 ws = Wl[src2*C_+tid];
      Wl[tid]      = csub(Wl[tid],      cmul(v.v0, ws));
      Wl[C_+tid]   = csub(Wl[C_+tid],   cmul(v.v1, ws));
    } else if (tid >= 64 && tid < 64 + C_*T_){
      int i = tid - 64;
      float2 hs = Hl[src2*C_*T_+i];
      Hl[i]        = csub(Hl[i],        cmul(v.v0, hs));
      Hl[C_*T_+i]  = csub(Hl[C_*T_+i],  cmul(v.v1, hs));
    }
  }

  // ---- background rounds (Z on the fly) ----
  for (int bak = 0; bak < K_; ++bak){
    float2 J0 = Jl[bak*S_+0], J1 = Jl[bak*S_+1];
    V2 v = round2(tid, hasB, (rr++)&1, redl, yA0,yA1,yB0,yB1, wA0,wA1,wB0,wB1,
        [&](int k)->float2 {
          float2 x0 = k ? xB0 : xA0;
          float2 x1 = k ? xB1 : xA1;
          int n = k ? nBs : nA;
          float2 z = cadd(cmul(J0, x0), cmul(J1, x1));
          return csub(z, Xl[(S_+bak)*N_ + n]);
        }, false, 0);
    if (tid < S_){
      float2 vv = tid ? v.v1 : v.v0;
      Wl[tid*C_+0]      = csub(Wl[tid*C_+0], cmul(vv, J0));
      Wl[tid*C_+1]      = csub(Wl[tid*C_+1], cmul(vv, J1));
      Wl[tid*C_+S_+bak] = cadd(Wl[tid*C_+S_+bak], vv);
    }
  }

  // ---- tap rounds ----
  for (int sc = 0; sc < C_; ++sc){
    for (int tap = 0; tap < T_; ++tap){
      int lag = DLY - tap;
      V2 v = round2(tid, hasB, (rr++)&1, redl, yA0,yA1,yB0,yB1, wA0,wA1,wB0,wB1,
          [&](int k)->float2 {
            int n = (k ? nBs : nA) - lag;
            return (n >= 0) ? Xl[sc*N_ + n] : make_float2(0.f, 0.f);
          }, false, 0);
      if (tid < S_){
        int idx = (tid*C_+sc)*T_+tap;
        Hl[idx] = cadd(Hl[idx], tid ? v.v1 : v.v0);
      }
    }
  }

  __syncthreads();   // all W/H updates visible

  if (!FINAL){
    Yg[((size_t)p*S_+0)*N_+nA] = yA0;
    Yg[((size_t)p*S_+1)*N_+nA] = yA1;
    if (hasB){
      Yg[((size_t)p*S_+0)*N_+nB] = yB0;
      Yg[((size_t)p*S_+1)*N_+nB] = yB1;
    }
    if (tid < S_*C_)    Wg[(size_t)p*S_*C_ + tid]    = Wl[tid];
    if (tid < S_*C_*T_) Hg[(size_t)p*S_*C_*T_ + tid] = Hl[tid];
  } else {
    bg_update(tid, Wl, Hl, Al, Jl, cx, cb);   // final J

    float2 oA0 = make_float2(0.f,0.f), oA1 = oA0, oB0 = oA0, oB1 = oA0;
    #pragma unroll
    for (int d = 0; d < C_; ++d){
      float2 x = Xl[d*N_+nA];
      oA0 = cadd(oA0, cmul(Wl[d],    x));
      oA1 = cadd(oA1, cmul(Wl[C_+d], x));
    }
    #pragma unroll
    for (int t = 0; t < T_; ++t){
      int m = nA - (DLY - t);
      if (m >= 0){
        #pragma unroll
        for (int d = 0; d < C_; ++d){
          float2 x = Xl[d*N_+m];
          oA0 = csub(oA0, cmul(Hl[d*T_+t],      x));
          oA1 = csub(oA1, cmul(Hl[(C_+d)*T_+t], x));
        }
      }
    }
    if (hasB){
      #pragma unroll
      for (int d = 0; d < C_; ++d){
        float2 x = Xl[d*N_+nB];
        oB0 = cadd(oB0, cmul(Wl[d],    x));
        oB1 = cadd(oB1, cmul(Wl[C_+d], x));
      }
      #pragma unroll
      for (int t = 0; t < T_; ++t){
        int m = nB - (DLY - t);
        #pragma unroll
        for (int d = 0; d < C_; ++d){
          float2 x = Xl[d*N_+m];
          oB0 = csub(oB0, cmul(Hl[d*T_+t],      x));
          oB1 = csub(oB1, cmul(Hl[(C_+d)*T_+t], x));
        }
      }
    }

    if (tid == 0){
      dc Bm[2][2];
      #pragma unroll
      for (int s2 = 0; s2 < S_; ++s2)
        #pragma unroll
        for (int k = 0; k < S_; ++k){
          dc acc = d_of(Wl[s2*C_+k]);
          #pragma unroll
          for (int c = 0; c < K_; ++c)
            acc = dadd(acc, dmul(d_of(Wl[s2*C_+S_+c]), d_of(Jl[c*S_+k])));
          Bm[s2][k] = acc;
        }
      dc G00 = dc{Bm[0][0].x + PB_EPSD, Bm[0][0].y};
      dc G01 = Bm[1][0];
      dc G10 = Bm[0][1];
      dc G11 = dc{Bm[1][1].x + PB_EPSD, Bm[1][1].y};
      dc det = dsub(dmul(G00, G11), dmul(G01, G10));
      dc a0 = ddiv(G11, det);
      dc a1 = ddiv(dc{-G10.x, -G10.y}, det);
      Al[0] = make_float2((float)a0.x, (float)a0.y);
      Al[1] = make_float2((float)a1.x, (float)a1.y);
    }
    __syncthreads();
    float2 s0 = Al[0], s1 = Al[1];
    out2[((size_t)(b*S_+0)*F_ + f)*N_ + nA] = cmul(oA0, s0);
    out2[((size_t)(b*S_+1)*F_ + f)*N_ + nA] = cmul(oA1, s1);
    if (hasB){
      out2[((size_t)(b*S_+0)*F_ + f)*N_ + nB] = cmul(oB0, s0);
      out2[((size_t)(b*S_+1)*F_ + f)*N_ + nB] = cmul(oB1, s1);
    }
  }
}

// ---------------------------------------------------------------------------
extern "C" void kernel_launch(void* const* d_in, const int* in_sizes, int n_in,
                              void* d_out, int out_size, void* d_ws, size_t ws_size,
                              hipStream_t stream)
{
  const float* Xre = (const float*)d_in[0];
  const float* Xim = (const float*)d_in[1];
  int B = in_sizes[0] / (C_*F_*N_);
  int P = B*F_;

  float2* Yg    = (float2*)d_ws;
  float2* Wg    = Yg    + (size_t)P*S_*N_;
  float2* Hg    = Wg    + (size_t)P*S_*C_;
  float2* Cxxg  = Hg    + (size_t)P*S_*C_*T_;
  float2* Cbxg  = Cxxg  + (size_t)P*C_*C_;
  float*  deng0 = (float*)(Cbxg + (size_t)P*C_*T_*C_);
  float*  deng1 = deng0 + (size_t)B*S_*N_;
  float*  gsum0 = deng1 + (size_t)B*S_*N_;
  float*  gsum1 = gsum0 + (size_t)B*S_;
  float2* out2  = (float2*)d_out;

  size_t zeroBytes = (2*(size_t)B*S_*N_ + 2*(size_t)B*S_) * sizeof(float);
  int WG = B*S_*8*16;

  hipMemsetAsync(deng0, 0, zeroBytes, stream);
  // iteration 0 (covariances computed inside k_main<FIRST>)
  k_weights_x<<<WG, 128, 0, stream>>>(Xre, Xim, deng0, gsum0);
  k_main<true,false><<<P, 512, 0, stream>>>(Xre, Xim, Yg, Wg, Hg, Cxxg, Cbxg,
                                            deng0, gsum0, nullptr);
  // iteration 1 + finalization
  k_weights_y<<<WG, 128, 0, stream>>>(Yg, deng1, gsum1);
  k_main<false,true><<<P, 512, 0, stream>>>(Xre, Xim, Yg, Wg, Hg, Cxxg, Cbxg,
                                            deng1, gsum1, out2);
}